// Round 7
// baseline (71.923 us; speedup 1.0000x reference)
//
#include <hip/hip_runtime.h>

// Problem constants (from reference)
#define B 1024
#define R 256
#define D 512
#define G 4

#define LOG2E 1.44269504088896340736f

// Workspace layout (float offsets). Total = 2,886,656 floats = 11.55 MB (same as R6's proven footprint).
// PB: per (r, chunk-of-4-d): [th(4) | fa(4) | q0(4) | q1(4) | q2(4) | q3(4)] = 24 floats
//   fa = -kappa*tanh(isp)*LOG2E ;  t = (x - th)*fa ;  sigmoid = 1/(1+exp2(t))
//   qg = sigmoid(ml)*tanh(esp)*softmax(A)_g
#define OFF_PB   0                       // [R][128][24]
#define OFF_EPI  (R*128*24)              // [R][12]  {offe0..3, gm0..3, k8e, hw, pad, pad}
#define OFF_PART (OFF_EPI + R*12)        // [R][2 dh][B][4 g] raw acc partials
#define NBT 16                           // b-tiles (64 b per block)

typedef float f2 __attribute__((ext_vector_type(2)));
static __device__ __forceinline__ f2 mk2(float a, float b) { f2 v; v.x = a; v.y = b; return v; }

// fast device math (1-ulp exp2/rcp based; inputs here are small/clamped)
__device__ __forceinline__ float rcp_f(float v)  { return __builtin_amdgcn_rcpf(v); }
__device__ __forceinline__ float exp2_f(float v) { return __builtin_amdgcn_exp2f(v); }
__device__ __forceinline__ float sig_f(float v)  { return rcp_f(1.0f + exp2_f(-v * LOG2E)); }
__device__ __forceinline__ float tanh_f(float v) {
    const float q2 = exp2_f(v * (2.0f * LOG2E));
    return (q2 - 1.0f) * rcp_f(q2 + 1.0f);
}

// ---------------- Kernel 1: fold all b-independent math ----------------
__global__ __launch_bounds__(256)
void sge_precompute(const float* __restrict__ th,  const float* __restrict__ isp,
                    const float* __restrict__ esp, const float* __restrict__ ml,
                    const float* __restrict__ lk,  const float* __restrict__ gl,
                    const float* __restrict__ tg,  const float* __restrict__ gml,
                    const float* __restrict__ kf,  const float* __restrict__ hw,
                    float* __restrict__ ws)
{
    const int r   = blockIdx.x;
    const int tid = threadIdx.x;
    __shared__ float4 red[256];

    float kappa = exp2_f(lk[0] * LOG2E);
    kappa = fminf(fmaxf(kappa, 0.5f), 50.0f);

    float4 psum = make_float4(0.f, 0.f, 0.f, 0.f);
    for (int d = tid; d < D; d += 256) {
        const int idx = r * D + d;
        const float thv  = th[idx];
        const float ineq = tanh_f(isp[idx]);
        const float es   = tanh_f(esp[idx]);
        const float mm   = sig_f(ml[idx]);
        // softmax over g (axis 0) of group_logits[:, d]
        const float g0 = gl[0*D + d], g1 = gl[1*D + d], g2 = gl[2*D + d], g3 = gl[3*D + d];
        const float mx = fmaxf(fmaxf(g0, g1), fmaxf(g2, g3));
        const float e0 = exp2_f((g0 - mx) * LOG2E), e1 = exp2_f((g1 - mx) * LOG2E);
        const float e2 = exp2_f((g2 - mx) * LOG2E), e3 = exp2_f((g3 - mx) * LOG2E);
        const float inv = 1.0f / (e0 + e1 + e2 + e3);
        const float a0 = e0 * inv, a1 = e1 * inv, a2 = e2 * inv, a3 = e3 * inv;

        const float fa = -kappa * ineq * LOG2E;   // exp2((x-th)*fa) == exp(-kappa*ineq*(x-th))
        const float s  = mm * es;
        const float s0 = s * a0, s1 = s * a1, s2 = s * a2, s3 = s * a3;

        const int chunk = d >> 2, j = d & 3;
        float* pc = ws + OFF_PB + ((size_t)r * 128 + chunk) * 24;
        pc[j]      = thv;
        pc[4 + j]  = fa;
        pc[8 + j]  = s0;
        pc[12 + j] = s1;
        pc[16 + j] = s2;
        pc[20 + j] = s3;
        psum.x += s0; psum.y += s1; psum.z += s2; psum.w += s3;
    }
    red[tid] = psum;
    __syncthreads();
    for (int s = 128; s > 0; s >>= 1) {
        if (tid < s) {
            red[tid].x += red[tid + s].x;
            red[tid].y += red[tid + s].y;
            red[tid].z += red[tid + s].z;
            red[tid].w += red[tid + s].w;
        }
        __syncthreads();
    }
    if (tid == 0) {
        const float4 base = red[0];
        const float gm0 = sig_f(gml[r * G + 0]);
        const float gm1 = sig_f(gml[r * G + 1]);
        const float gm2 = sig_f(gml[r * G + 2]);
        const float gm3 = sig_f(gml[r * G + 3]);
        const float en  = gm0 + gm1 + gm2 + gm3 + 1e-6f;
        const float k   = sig_f(kf[r]) * en;
        float* epi = ws + OFF_EPI + r * 12;
        // pg_g = sigmoid(12*acc_g - 6*(base_g+tg_g))  ->  exp2 arg = fma(C12, acc, offe)
        epi[0] = 6.0f * (base.x + tg[r * G + 0]) * LOG2E;
        epi[1] = 6.0f * (base.y + tg[r * G + 1]) * LOG2E;
        epi[2] = 6.0f * (base.z + tg[r * G + 2]) * LOG2E;
        epi[3] = 6.0f * (base.w + tg[r * G + 3]) * LOG2E;
        epi[4] = gm0; epi[5] = gm1; epi[6] = gm2; epi[7] = gm3;
        epi[8] = 8.0f * k * LOG2E;   // z = sigmoid(8*score - 8k) -> exp2 arg = fma(C8, score, k8e)
        epi[9] = hw[r];
        epi[10] = 0.f; epi[11] = 0.f;
    }
}

// ---------------- Kernel 2: the 134M-element hot loop ----------------
// Grid: 16 b-tiles x (16 r-blocks x 2 d-halves) = 512 blocks (2/CU, LDS-capped).
// Block: 512 thr = 8 waves; wave w owns an r-PAIR (r0 = rblk*16 + 2w, r1 = r0+1)
// over 64 b (lane = b) x 256 d (this block's d-half). One x ds_read feeds BOTH
// r's -> LDS read traffic halved. x staged ONCE per block (1 barrier total).
// Params: 4-d chunks of 24 floats/r via wave-uniform s_load; the staggered A/B
// prefetch (p0B loaded during r0-compute, p1B during r1-compute) keeps the live
// SGPR set <= ~72 (fits the ~102/wave budget, unlike the 96-float chunks of R6).
// Compute: packed-f32 d-pairs, quad-rcp (1 v_rcp per 4 sigmoids = 1.25 trans/elem).
__global__ __launch_bounds__(512, 4)
void sge_main(const float* __restrict__ x, const float* __restrict__ ws,
              float* __restrict__ part)
{
    __shared__ float xl[64 * 260];   // 64 b rows x 256 d, pitch 260 (R3's conflict-free pattern)

    const int tid  = threadIdx.x;
    const int lane = tid & 63;
    const int w    = __builtin_amdgcn_readfirstlane(tid >> 6);  // force wave-uniform
    const int bt   = blockIdx.x;          // 0..15
    const int rbdh = blockIdx.y;          // 0..31
    const int rblk = rbdh >> 1;           // 0..15
    const int dh   = rbdh & 1;            // d-half 0..1
    const int r0   = rblk * 16 + 2 * w;
    const int r1   = r0 + 1;

    const float* pb0 = ws + OFF_PB + (size_t)r0 * (128 * 24) + (size_t)dh * (64 * 24);
    const float* pb1 = ws + OFF_PB + (size_t)r1 * (128 * 24) + (size_t)dh * (64 * 24);

    // ---- stage this block's x half-tile: 64 b x 256 d, once ----
    for (int i = tid; i < 64 * 64; i += 512) {
        const int row = i >> 6, c4 = i & 63;
        const float4 v = *reinterpret_cast<const float4*>(
            &x[(size_t)(bt * 64 + row) * D + dh * 256 + c4 * 4]);
        *reinterpret_cast<float4*>(&xl[row * 260 + c4 * 4]) = v;
    }
    __syncthreads();

    f2 a00 = mk2(0.f,0.f), a01 = mk2(0.f,0.f), a02 = mk2(0.f,0.f), a03 = mk2(0.f,0.f);
    f2 a10 = mk2(0.f,0.f), a11 = mk2(0.f,0.f), a12 = mk2(0.f,0.f), a13 = mk2(0.f,0.f);

    float p0A[24], p0B[24], p1A[24], p1B[24];
    float4 xA, xB;

    auto loadP = [](float (&p)[24], const float* base, int c) {
        const float* pc = base + (size_t)c * 24;
        #pragma unroll
        for (int j = 0; j < 24; ++j) p[j] = pc[j];
    };
    auto loadX = [&](float4& xq, int c) {
        xq = *reinterpret_cast<const float4*>(&xl[lane * 260 + c * 4]);
    };
    auto compute = [](const float (&p)[24], const float4& xq,
                      f2& g0, f2& g1, f2& g2, f2& g3) {
        const f2 x0 = mk2(xq.x, xq.y), x1 = mk2(xq.z, xq.w);
        const f2 t0 = (x0 - mk2(p[0], p[1])) * mk2(p[4], p[5]);   // v_pk_add(neg) / v_pk_mul
        const f2 t1 = (x1 - mk2(p[2], p[3])) * mk2(p[6], p[7]);
        f2 q0, q1;
        q0.x = exp2_f(t0.x); q0.y = exp2_f(t0.y);
        q1.x = exp2_f(t1.x); q1.y = exp2_f(t1.y);
        const f2 b0 = q0 + 1.0f, b1 = q1 + 1.0f;
        const float P0 = b0.x * b0.y, P1 = b1.x * b1.y;
        const float r4 = rcp_f(P0 * P1);                          // ONE rcp per 4 sigmoids
        const float i0 = r4 * P1, i1 = r4 * P0;                   // 1/P0, 1/P1
        const f2 c0 = __builtin_shufflevector(b0, b0, 1, 0) * i0; // {1/b0.x, 1/b0.y}
        const f2 c1 = __builtin_shufflevector(b1, b1, 1, 0) * i1;
        g0 = __builtin_elementwise_fma(mk2(p[8],  p[9]),  c0, g0);
        g0 = __builtin_elementwise_fma(mk2(p[10], p[11]), c1, g0);
        g1 = __builtin_elementwise_fma(mk2(p[12], p[13]), c0, g1);
        g1 = __builtin_elementwise_fma(mk2(p[14], p[15]), c1, g1);
        g2 = __builtin_elementwise_fma(mk2(p[16], p[17]), c0, g2);
        g2 = __builtin_elementwise_fma(mk2(p[18], p[19]), c1, g2);
        g3 = __builtin_elementwise_fma(mk2(p[20], p[21]), c0, g3);
        g3 = __builtin_elementwise_fma(mk2(p[22], p[23]), c1, g3);
    };

    // prologue
    loadP(p0A, pb0, 0); loadP(p1A, pb1, 0); loadX(xA, 0);

    #pragma unroll 1
    for (int c = 0; c < 64; c += 2) {
        loadX(xB, c + 1);
        loadP(p0B, pb0, c + 1);
        compute(p0A, xA, a00, a01, a02, a03);
        loadP(p1B, pb1, c + 1);
        compute(p1A, xA, a10, a11, a12, a13);
        const int cn = (c + 2 < 64) ? (c + 2) : 0;   // tail prefetch dead but harmless
        loadX(xA, cn);
        loadP(p0A, pb0, cn);
        compute(p0B, xB, a00, a01, a02, a03);
        loadP(p1A, pb1, cn);
        compute(p1B, xB, a10, a11, a12, a13);
    }

    // ---- write raw acc partials (d-parity folded); finalize merges d-halves ----
    {
        float4 v0 = make_float4(a00.x + a00.y, a01.x + a01.y, a02.x + a02.y, a03.x + a03.y);
        float4 v1 = make_float4(a10.x + a10.y, a11.x + a11.y, a12.x + a12.y, a13.x + a13.y);
        float* pa0 = part + ((size_t)(r0 * 2 + dh) * B + bt * 64 + lane) * 4;
        float* pa1 = part + ((size_t)(r1 * 2 + dh) * B + bt * 64 + lane) * 4;
        *reinterpret_cast<float4*>(pa0) = v0;
        *reinterpret_cast<float4*>(pa1) = v1;
    }
}

// ---------------- Kernel 3: combine d-halves, nonlinear chain, reduce r ----------------
// Grid: 16 blocks (one per 64-b group) x 512 thr = 64 lanes x 8 r-slices of 32 r.
__global__ __launch_bounds__(512)
void sge_finalize(const float* __restrict__ part, const float* __restrict__ ws,
                  const float* __restrict__ hb, float* __restrict__ y)
{
    __shared__ float red[512];
    const int tid   = threadIdx.x;
    const int lane  = tid & 63;       // b within group
    const int slice = tid >> 6;       // 0..7 (r-slices of 32)
    const int bg    = blockIdx.x;     // 0..15
    const int b     = bg * 64 + lane;
    const float C12 = -12.0f * LOG2E;
    const float C8  = -8.0f  * LOG2E;

    float s = 0.f;
    for (int rr = 0; rr < 32; ++rr) {
        const int r = slice * 32 + rr;
        const float4 v0 = *reinterpret_cast<const float4*>(part + ((size_t)(r * 2 + 0) * B + b) * 4);
        const float4 v1 = *reinterpret_cast<const float4*>(part + ((size_t)(r * 2 + 1) * B + b) * 4);
        const float a0 = v0.x + v1.x;
        const float a1 = v0.y + v1.y;
        const float a2 = v0.z + v1.z;
        const float a3 = v0.w + v1.w;
        const float* epi = ws + OFF_EPI + r * 12;
        const float pg0 = rcp_f(1.0f + exp2_f(fmaf(C12, a0, epi[0])));
        const float pg1 = rcp_f(1.0f + exp2_f(fmaf(C12, a1, epi[1])));
        const float pg2 = rcp_f(1.0f + exp2_f(fmaf(C12, a2, epi[2])));
        const float pg3 = rcp_f(1.0f + exp2_f(fmaf(C12, a3, epi[3])));
        float score = pg0 * epi[4];
        score = fmaf(pg1, epi[5], score);
        score = fmaf(pg2, epi[6], score);
        score = fmaf(pg3, epi[7], score);
        const float z = rcp_f(1.0f + exp2_f(fmaf(C8, score, epi[8])));
        s = fmaf(epi[9], z, s);
    }
    red[tid] = s;
    __syncthreads();
    if (slice == 0) {
        float tot = hb[0];
        #pragma unroll
        for (int k = 0; k < 8; ++k) tot += red[k * 64 + lane];
        y[b] = tot;
    }
}

extern "C" void kernel_launch(void* const* d_in, const int* in_sizes, int n_in,
                              void* d_out, int out_size, void* d_ws, size_t ws_size,
                              hipStream_t stream)
{
    const float* x   = (const float*)d_in[0];
    const float* th  = (const float*)d_in[1];
    const float* isp = (const float*)d_in[2];
    const float* esp = (const float*)d_in[3];
    const float* ml  = (const float*)d_in[4];
    const float* lk  = (const float*)d_in[5];
    const float* gl  = (const float*)d_in[6];
    const float* tg  = (const float*)d_in[7];
    const float* gml = (const float*)d_in[8];
    const float* kf  = (const float*)d_in[9];
    const float* hw  = (const float*)d_in[10];
    const float* hb  = (const float*)d_in[11];
    float* ws = (float*)d_ws;
    float* y  = (float*)d_out;

    sge_precompute<<<R, 256, 0, stream>>>(th, isp, esp, ml, lk, gl, tg, gml, kf, hw, ws);
    sge_main<<<dim3(NBT, 32), 512, 0, stream>>>(x, ws, ws + OFF_PART);
    sge_finalize<<<NBT, 512, 0, stream>>>(ws + OFF_PART, ws, hb, y);
}